// Round 9
// baseline (514.972 us; speedup 1.0000x reference)
//
#include <hip/hip_runtime.h>
#include <hip/hip_bf16.h>
#include <stdint.h>

#define SEQ 4096
#define DIM 2048
#define NH 16
#define NKV 4
#define HD 128
#define KVLD 1024   /* K|V fused row stride in KVb */

// External I/O is FP32 (proven round 2/6); internal tensors bf16.

using frag8 = __attribute__((ext_vector_type(8))) short;
using f32x4 = __attribute__((ext_vector_type(4))) float;

union VecU { ushort u[8]; uint4 v; };

__device__ __forceinline__ float bf2f(ushort u) {
    union { uint32_t u; float f; } v; v.u = ((uint32_t)u) << 16; return v.f;
}
__device__ __forceinline__ ushort f2bf(float f) {
    union { float f; uint32_t u; } v; v.f = f;
    uint32_t r = v.u + 0x7fffu + ((v.u >> 16) & 1u);
    return (ushort)(r >> 16);
}

__device__ __forceinline__ void glds16(const void* g, void* l) {
    __builtin_amdgcn_global_load_lds(
        (const __attribute__((address_space(1))) void*)g,
        (__attribute__((address_space(3))) void*)l, 16, 0, 0);
}

// ---------------------------------------------------------------------------
// fp32 -> bf16 flat convert (8 elems/thread).
// ---------------------------------------------------------------------------
__global__ __launch_bounds__(256) void cvt_kernel(
    const float* __restrict__ src, ushort* __restrict__ dst)
{
    size_t i = ((size_t)blockIdx.x * 256 + threadIdx.x) * 8;
    float4 f0 = *(const float4*)&src[i];
    float4 f1 = *(const float4*)&src[i + 4];
    VecU t;
    t.u[0] = f2bf(f0.x); t.u[1] = f2bf(f0.y); t.u[2] = f2bf(f0.z); t.u[3] = f2bf(f0.w);
    t.u[4] = f2bf(f1.x); t.u[5] = f2bf(f1.y); t.u[6] = f2bf(f1.z); t.u[7] = f2bf(f1.w);
    *(uint4*)&dst[i] = t.v;
}

// ---------------------------------------------------------------------------
// Merged weight transpose: wq|wk|wv fp32 [K][N] -> bf16 [N][K] in one launch.
// Grid (96, 64): bx<64 -> wq (N=2048 -> WqT); bx in [64,80) -> wk (N=512 ->
// KVT); bx in [80,96) -> wv (N=512 -> KVT+512*DIM). K=2048 for all.
// ---------------------------------------------------------------------------
__global__ __launch_bounds__(256) void convW_kernel(
    const float* __restrict__ wq, const float* __restrict__ wk,
    const float* __restrict__ wv, ushort* __restrict__ WqT,
    ushort* __restrict__ KVT)
{
    __shared__ ushort T[32][36];
    const int K = DIM;
    const float* src; ushort* dst; int N, bn;
    int bx = blockIdx.x;
    if (bx < 64)      { src = wq; dst = WqT;                     N = DIM; bn = bx * 32; }
    else if (bx < 80) { src = wk; dst = KVT;                     N = 512; bn = (bx - 64) * 32; }
    else              { src = wv; dst = KVT + (size_t)512 * DIM; N = 512; bn = (bx - 80) * 32; }

    int r  = threadIdx.x >> 3;
    int c4 = (threadIdx.x & 7) * 4;
    int bk = blockIdx.y * 32;
    float4 v = *(const float4*)&src[(size_t)(bk + r) * N + bn + c4];
    T[r][c4]     = f2bf(v.x); T[r][c4 + 1] = f2bf(v.y);
    T[r][c4 + 2] = f2bf(v.z); T[r][c4 + 3] = f2bf(v.w);
    __syncthreads();
    ushort4 o;
    o.x = T[c4][r]; o.y = T[c4 + 1][r]; o.z = T[c4 + 2][r]; o.w = T[c4 + 3][r];
    *(ushort4*)&dst[(size_t)(bn + r) * K + bk + c4] = o;
}

// ---------------------------------------------------------------------------
// fp32 [K][N] -> bf16 transposed [N][K], 32x32 tiles (wo, post-attn).
// ---------------------------------------------------------------------------
__global__ __launch_bounds__(256) void convT_kernel(
    const float* __restrict__ src, ushort* __restrict__ dst, int K, int N)
{
    __shared__ ushort T[32][36];
    int r  = threadIdx.x >> 3;
    int c4 = (threadIdx.x & 7) * 4;
    int bk = blockIdx.y * 32, bn = blockIdx.x * 32;
    float4 v = *(const float4*)&src[(size_t)(bk + r) * N + bn + c4];
    T[r][c4]     = f2bf(v.x); T[r][c4 + 1] = f2bf(v.y);
    T[r][c4 + 2] = f2bf(v.z); T[r][c4 + 3] = f2bf(v.w);
    __syncthreads();
    ushort4 o;
    o.x = T[c4][r]; o.y = T[c4 + 1][r]; o.z = T[c4 + 2][r]; o.w = T[c4 + 3][r];
    *(ushort4*)&dst[(size_t)(bn + r) * K + bk + c4] = o;
}

// ---------------------------------------------------------------------------
// Merged post-projection prep, one launch (all three parts independent):
//   b <  16384          : RoPE on Qb (16 heads, stride DIM, 1/sqrt(HD) folded)
//   16384 <= b < 20480  : RoPE on KVb K-half (4 heads, stride KVLD, cols<512)
//   b >= 20480          : V transpose KVb[t][512+d] -> VT[d][t] (reads cols>=512)
// ---------------------------------------------------------------------------
__global__ __launch_bounds__(256) void fuse3_kernel(
    ushort* __restrict__ Qb, ushort* __restrict__ KVb, ushort* __restrict__ VT,
    const float* __restrict__ Cos, const float* __restrict__ Sin)
{
    __shared__ ushort T[32][36];
    int b = blockIdx.x;
    if (b < 20480) {
        ushort* X; int log2nh, strideT, idx; float osc;
        if (b < 16384) { X = Qb;  log2nh = 4; strideT = DIM;  osc = 0.08838834764831845f; idx = b * 256 + threadIdx.x; }
        else           { X = KVb; log2nh = 2; strideT = KVLD; osc = 1.0f; idx = (b - 16384) * 256 + threadIdx.x; }
        int p = idx & 63;
        int h = (idx >> 6) & ((1 << log2nh) - 1);
        int t = idx >> (6 + log2nh);
        size_t base = (size_t)t * strideT + (size_t)h * 128 + 2 * p;
        ushort2 xv = *(ushort2*)&X[base];
        float x1 = bf2f(xv.x), x2 = bf2f(xv.y);
        float c = Cos[t * 64 + p], s = Sin[t * 64 + p];
        ushort2 ov;
        ov.x = f2bf((x1 * c - x2 * s) * osc);
        ov.y = f2bf((x1 * s + x2 * c) * osc);
        *(ushort2*)&X[base] = ov;
    } else {
        int v  = b - 20480;
        int bd = (v & 15) * 32;            // d-block
        int bt = (v >> 4) * 32;            // t-block
        int r  = threadIdx.x >> 3;
        int c4 = (threadIdx.x & 7) * 4;
        ushort4 w = *(const ushort4*)&KVb[(size_t)(bt + r) * KVLD + 512 + bd + c4];
        T[r][c4] = w.x; T[r][c4 + 1] = w.y; T[r][c4 + 2] = w.z; T[r][c4 + 3] = w.w;
        __syncthreads();
        ushort4 o;
        o.x = T[c4][r]; o.y = T[c4 + 1][r]; o.z = T[c4 + 2][r]; o.w = T[c4 + 3][r];
        *(ushort4*)&VT[(size_t)(bd + r) * SEQ + bt + c4] = o;
    }
}

// ---------------------------------------------------------------------------
// m97-style GEMM: C[M][N] = A[M][K] @ BT[N][K]^T, bf16 in; CF: fp32/bf16 out.
// 128x128 tile, BK=32, global_load_lds(16B).
// ---------------------------------------------------------------------------
template <int CF>
__global__ __launch_bounds__(256) void gemm_tn(
    const ushort* __restrict__ A, const ushort* __restrict__ BT,
    void* __restrict__ C, int M, int N, int K)
{
    __shared__ ushort As[128 * 32];
    __shared__ ushort Bs[128 * 32];

    const int tid  = threadIdx.x;
    const int lane = tid & 63;
    const int wave = tid >> 6;
    const int bm   = blockIdx.y * 128;
    const int bn   = blockIdx.x * 128;
    const int wm   = (wave >> 1) * 64;
    const int wn   = (wave & 1) * 64;
    const int quad = lane >> 4;
    const int t16  = lane & 15;
    const int kg   = quad ^ ((t16 >> 1) & 3);

    f32x4 acc[4][4] = {};

    for (int k0 = 0; k0 < K; k0 += 32) {
        #pragma unroll
        for (int it = 0; it < 2; ++it) {
            int gid = it * 256 + tid;
            int r   = gid >> 2;
            int cs  = (gid & 3) ^ ((gid >> 3) & 3);
            glds16(&A[(size_t)(bm + r) * K + k0 + cs * 8],
                   &As[(it * 256 + wave * 64) * 8]);
            glds16(&BT[(size_t)(bn + r) * K + k0 + cs * 8],
                   &Bs[(it * 256 + wave * 64) * 8]);
        }
        __syncthreads();

        frag8 af[4], bf[4];
        #pragma unroll
        for (int i = 0; i < 4; ++i)
            af[i] = *(const frag8*)&As[(wm + i * 16 + t16) * 32 + kg * 8];
        #pragma unroll
        for (int j = 0; j < 4; ++j)
            bf[j] = *(const frag8*)&Bs[(wn + j * 16 + t16) * 32 + kg * 8];
        #pragma unroll
        for (int i = 0; i < 4; ++i)
            #pragma unroll
            for (int j = 0; j < 4; ++j)
                acc[i][j] = __builtin_amdgcn_mfma_f32_16x16x32_bf16(
                    af[i], bf[j], acc[i][j], 0, 0, 0);
        __syncthreads();
    }

    #pragma unroll
    for (int i = 0; i < 4; ++i)
        #pragma unroll
        for (int j = 0; j < 4; ++j)
            #pragma unroll
            for (int r = 0; r < 4; ++r) {
                int row = bm + wm + i * 16 + quad * 4 + r;
                int col = bn + wn + j * 16 + t16;
                if (CF) ((float*)C)[(size_t)row * N + col] = acc[i][j][r];
                else    ((ushort*)C)[(size_t)row * N + col] = f2bf(acc[i][j][r]);
            }
}

// ---------------------------------------------------------------------------
// Fused QKV projection GEMM: A[SEQ][DIM] @ BT[3072][DIM]^T.
// BT rows 0..2047 = WqT, rows 2048..3071 = KVT (wk|wv) — contiguous at Ab.
// Block-uniform C split (2048 is 128-aligned): cols < 2048 -> Qb (ld DIM),
// cols >= 2048 -> KVb (ld KVLD). Grid 24x32 = 768 blocks.
// ---------------------------------------------------------------------------
__global__ __launch_bounds__(256) void gemm_qkv(
    const ushort* __restrict__ A, const ushort* __restrict__ BT,
    ushort* __restrict__ Cq, ushort* __restrict__ Ckv)
{
    const int K = DIM;
    __shared__ ushort As[128 * 32];
    __shared__ ushort Bs[128 * 32];

    const int tid  = threadIdx.x;
    const int lane = tid & 63;
    const int wave = tid >> 6;
    const int bm   = blockIdx.y * 128;
    const int bn   = blockIdx.x * 128;
    const int wm   = (wave >> 1) * 64;
    const int wn   = (wave & 1) * 64;
    const int quad = lane >> 4;
    const int t16  = lane & 15;
    const int kg   = quad ^ ((t16 >> 1) & 3);

    f32x4 acc[4][4] = {};

    for (int k0 = 0; k0 < K; k0 += 32) {
        #pragma unroll
        for (int it = 0; it < 2; ++it) {
            int gid = it * 256 + tid;
            int r   = gid >> 2;
            int cs  = (gid & 3) ^ ((gid >> 3) & 3);
            glds16(&A[(size_t)(bm + r) * K + k0 + cs * 8],
                   &As[(it * 256 + wave * 64) * 8]);
            glds16(&BT[(size_t)(bn + r) * K + k0 + cs * 8],
                   &Bs[(it * 256 + wave * 64) * 8]);
        }
        __syncthreads();

        frag8 af[4], bf[4];
        #pragma unroll
        for (int i = 0; i < 4; ++i)
            af[i] = *(const frag8*)&As[(wm + i * 16 + t16) * 32 + kg * 8];
        #pragma unroll
        for (int j = 0; j < 4; ++j)
            bf[j] = *(const frag8*)&Bs[(wn + j * 16 + t16) * 32 + kg * 8];
        #pragma unroll
        for (int i = 0; i < 4; ++i)
            #pragma unroll
            for (int j = 0; j < 4; ++j)
                acc[i][j] = __builtin_amdgcn_mfma_f32_16x16x32_bf16(
                    af[i], bf[j], acc[i][j], 0, 0, 0);
        __syncthreads();
    }

    // Block-uniform output select.
    ushort* C;
    int ldc, cb;
    if (bn < 2048) { C = Cq;  ldc = DIM;  cb = 0; }
    else           { C = Ckv; ldc = KVLD; cb = 2048; }

    #pragma unroll
    for (int i = 0; i < 4; ++i)
        #pragma unroll
        for (int j = 0; j < 4; ++j)
            #pragma unroll
            for (int r = 0; r < 4; ++r) {
                int row = bm + wm + i * 16 + quad * 4 + r;
                int col = bn + wn + j * 16 + t16;
                C[(size_t)row * ldc + (col - cb)] = f2bf(acc[i][j][r]);
            }
}

// ---------------------------------------------------------------------------
// Flash attention, causal, GQA, bf16 internal; head-paired blocks + KV-split
// (round-8 structure, 148 us). NEW this round: KVBLK=32 with K/V LDS
// double-buffer + software prefetch — per tile: issue next tile's 4 uint4
// global loads -> compute current tile -> write staged regs to other buffer
// -> one barrier. HBM/L2 latency (~500cy) hides under ~600cy compute; barrier
// density unchanged (1 per 32 KV vs 2 per 64 KV). LDS 48.1 KB -> 3 blocks/CU
// with margin. Staged regs = 16 VGPR (round-2's spill was 32 + tight clamp;
// keep (256,2) — VGPR sentinel: WRITE_SIZE must stay 25,600 KB).
// Grid (8, 96), heavy-first dispatch:
//   by <  64: qt = 63-(by>>1) in [32,63]; chunk c = by&1 of KV range in
//             contiguous halves (c0 mask-free). UNNORMALIZED partial o +
//             per-row (l, m) — exact flash split-k. c0 -> Oev, c1 -> Oab.
//   by >= 64: qt = 95-by in [0,31], unsplit, normalized direct write.
// combine_kernel merges rows 2048+ exactly. Spec-softmax (m=0 init,
// lane-local trigger, full fixup if __any(lm > m+8) — never for this data,
// exact for any). Row-sum via ones-MFMA. Scores pre-scaled (1/sqrt(HD) in
// Q). T5 setprio on MFMA clusters.
// ---------------------------------------------------------------------------
__global__ __launch_bounds__(256, 2) void attn_kernel(
    const ushort* __restrict__ Q, const ushort* __restrict__ Kb,
    const ushort* __restrict__ VT, ushort* __restrict__ Oab,
    ushort* __restrict__ Oev, float2* __restrict__ lmE, float2* __restrict__ lmO)
{
    __shared__ ushort Ks[2][32][136];   // [buf][t][d], 272B rows (17x16B)
    __shared__ ushort Vt[2][128][40];   // [buf][d][t], 80B rows (5x16B)
    __shared__ ushort Sp[4][32][40];    // per-wave P: rows 0-15 head A, 16-31 head B

    const int tid  = threadIdx.x;
    const int lane = tid & 63;
    const int wave = tid >> 6;
    const int quad = lane >> 4;
    const int t16  = lane & 15;
    const int hp   = blockIdx.x;        // head pair 0..7
    const int hA   = 2 * hp;
    const int hB   = 2 * hp + 1;
    const int kvh  = hp >> 1;

    frag8 vONE;
    #pragma unroll
    for (int i = 0; i < 8; ++i) vONE[i] = (short)0x3F80;   // bf16 1.0

    const int by = (int)blockIdx.y;
    int qt, c, split;
    if (by < 64) { split = 1; qt = 63 - (by >> 1); c = by & 1; }
    else         { split = 0; qt = 95 - by;        c = 0;      }
    const int n  = qt + 1;                       // total 64-KV tiles
    const int q0 = qt * 64;
    const int qwave = q0 + wave * 16;
    const int tstart = (split && c) ? (n / 2) * 64 : 0;
    const int tend   = (split && !c) ? (n / 2) * 64 : n * 64;

    frag8 aQA[4], aQB[4];
    #pragma unroll
    for (int kk = 0; kk < 4; ++kk) {
        aQA[kk] = *(const frag8*)&Q[(size_t)(qwave + t16) * DIM + hA * HD + kk * 32 + quad * 8];
        aQB[kk] = *(const frag8*)&Q[(size_t)(qwave + t16) * DIM + hB * HD + kk * 32 + quad * 8];
    }

    f32x4 oA[8] = {}, oB[8] = {};
    f32x4 o9A = {0.f, 0.f, 0.f, 0.f};
    f32x4 o9B = {0.f, 0.f, 0.f, 0.f};
    float mA[4] = {0.f, 0.f, 0.f, 0.f};
    float mB[4] = {0.f, 0.f, 0.f, 0.f};

    // Staging registers (16 VGPR): 2 uint4 K + 2 uint4 V per thread per tile.
    uint4 kreg[2], vreg[2];
    // Per-thread slot indices (constant across tiles).
    const int kt0 = (tid)       >> 4, kc0 = ((tid)       & 15) * 8;
    const int kt1 = (tid + 256) >> 4, kc1 = ((tid + 256) & 15) * 8;
    const int vd0 = (tid)       >> 2, vq0 = ((tid)       & 3) * 8;
    const int vd1 = (tid + 256) >> 2, vq1 = ((tid + 256) & 3) * 8;

#define LOADREGS(T0)                                                          \
    {                                                                         \
        kreg[0] = *(const uint4*)&Kb[(size_t)((T0) + kt0) * KVLD + kvh * HD + kc0]; \
        kreg[1] = *(const uint4*)&Kb[(size_t)((T0) + kt1) * KVLD + kvh * HD + kc1]; \
        vreg[0] = *(const uint4*)&VT[(size_t)(kvh * HD + vd0) * SEQ + (T0) + vq0];  \
        vreg[1] = *(const uint4*)&VT[(size_t)(kvh * HD + vd1) * SEQ + (T0) + vq1];  \
    }
#define WRITELDS(B)                                                           \
    {                                                                         \
        *(uint4*)&Ks[B][kt0][kc0] = kreg[0];                                  \
        *(uint4*)&Ks[B][kt1][kc1] = kreg[1];                                  \
        *(uint4*)&Vt[B][vd0][vq0] = vreg[0];                                  \
        *(uint4*)&Vt[B][vd1][vq1] = vreg[1];                                  \
    }

    int cur = 0;
    LOADREGS(tstart);
    WRITELDS(0);
    __syncthreads();

    for (int t0 = tstart; t0 < tend; t0 += 32) {
        const bool pref = (t0 + 32 < tend);          // block-uniform
        if (pref) LOADREGS(t0 + 32);                 // issue early (T14)

        f32x4 sA0 = {0.f,0.f,0.f,0.f}, sA1 = {0.f,0.f,0.f,0.f};
        f32x4 sB0 = {0.f,0.f,0.f,0.f}, sB1 = {0.f,0.f,0.f,0.f};

        __builtin_amdgcn_s_setprio(1);
        #pragma unroll
        for (int kk = 0; kk < 4; ++kk) {
            frag8 b0 = *(const frag8*)&Ks[cur][2 * t16][kk * 32 + quad * 8];
            frag8 b1 = *(const frag8*)&Ks[cur][2 * t16 + 1][kk * 32 + quad * 8];
            sA0 = __builtin_amdgcn_mfma_f32_16x16x32_bf16(aQA[kk], b0, sA0, 0, 0, 0);
            sB0 = __builtin_amdgcn_mfma_f32_16x16x32_bf16(aQB[kk], b0, sB0, 0, 0, 0);
            sA1 = __builtin_amdgcn_mfma_f32_16x16x32_bf16(aQA[kk], b1, sA1, 0, 0, 0);
            sB1 = __builtin_amdgcn_mfma_f32_16x16x32_bf16(aQB[kk], b1, sB1, 0, 0, 0);
        }
        __builtin_amdgcn_s_setprio(0);

        const bool mLo = (t0 + 31 > qwave);          // wave-uniform

        // Fast path: speculative exp against running m; lane-local trigger.
        bool trig = false;
        #pragma unroll
        for (int r = 0; r < 4; ++r) {
            int q = qwave + quad * 4 + r;
            bool x0 = mLo && (t0 + 2 * t16 > q);
            bool x1 = mLo && (t0 + 2 * t16 + 1 > q);
            float vA0 = x0 ? -30000.f : sA0[r];
            float vA1 = x1 ? -30000.f : sA1[r];
            float vB0 = x0 ? -30000.f : sB0[r];
            float vB1 = x1 ? -30000.f : sB1[r];
            float lmA = fmaxf(vA0, vA1);
            float lmB = fmaxf(vB0, vB1);
            trig |= (lmA > mA[r] + 8.f) | (lmB > mB[r] + 8.f);
            float eA0 = __expf(vA0 - mA[r]);
            float eA1 = __expf(vA1 - mA[r]);
            float eB0 = __expf(vB0 - mB[r]);
            float eB1 = __expf(vB1 - mB[r]);
            *(uint*)&Sp[wave][quad * 4 + r][2 * t16] =
                (uint)f2bf(eA0) | ((uint)f2bf(eA1) << 16);
            *(uint*)&Sp[wave][16 + quad * 4 + r][2 * t16] =
                (uint)f2bf(eB0) | ((uint)f2bf(eB1) << 16);
        }

        // Rare fixup: full cross-lane max, rescale, recompute + rewrite P.
        if (__any(trig)) {
            #pragma unroll
            for (int r = 0; r < 4; ++r) {
                int q = qwave + quad * 4 + r;
                bool x0 = mLo && (t0 + 2 * t16 > q);
                bool x1 = mLo && (t0 + 2 * t16 + 1 > q);
                float vA0 = x0 ? -30000.f : sA0[r];
                float vA1 = x1 ? -30000.f : sA1[r];
                float vB0 = x0 ? -30000.f : sB0[r];
                float vB1 = x1 ? -30000.f : sB1[r];
                float rmA = fmaxf(vA0, vA1);
                float rmB = fmaxf(vB0, vB1);
                rmA = fmaxf(rmA, __shfl_xor(rmA, 1));
                rmA = fmaxf(rmA, __shfl_xor(rmA, 2));
                rmA = fmaxf(rmA, __shfl_xor(rmA, 4));
                rmA = fmaxf(rmA, __shfl_xor(rmA, 8));
                rmB = fmaxf(rmB, __shfl_xor(rmB, 1));
                rmB = fmaxf(rmB, __shfl_xor(rmB, 2));
                rmB = fmaxf(rmB, __shfl_xor(rmB, 4));
                rmB = fmaxf(rmB, __shfl_xor(rmB, 8));
                float mnA = fmaxf(mA[r], rmA);
                float mnB = fmaxf(mB[r], rmB);
                float alA = __expf(mA[r] - mnA);
                float alB = __expf(mB[r] - mnB);
                #pragma unroll
                for (int j = 0; j < 8; ++j) { oA[j][r] *= alA; oB[j][r] *= alB; }
                o9A[r] *= alA; o9B[r] *= alB;
                mA[r] = mnA; mB[r] = mnB;
                float eA0 = __expf(vA0 - mnA);
                float eA1 = __expf(vA1 - mnA);
                float eB0 = __expf(vB0 - mnB);
                float eB1 = __expf(vB1 - mnB);
                *(uint*)&Sp[wave][quad * 4 + r][2 * t16] =
                    (uint)f2bf(eA0) | ((uint)f2bf(eA1) << 16);
                *(uint*)&Sp[wave][16 + quad * 4 + r][2 * t16] =
                    (uint)f2bf(eB0) | ((uint)f2bf(eB1) << 16);
            }
        }

        frag8 aPA0 = *(const frag8*)&Sp[wave][t16][quad * 8];
        frag8 aPB0 = *(const frag8*)&Sp[wave][16 + t16][quad * 8];
        __builtin_amdgcn_s_setprio(1);
        #pragma unroll
        for (int j = 0; j < 8; ++j) {
            frag8 bV = *(const frag8*)&Vt[cur][j * 16 + t16][quad * 8];
            oA[j] = __builtin_amdgcn_mfma_f32_16x16x32_bf16(aPA0, bV, oA[j], 0, 0, 0);
            oB[j] = __builtin_amdgcn_mfma_f32_16x16x32_bf16(aPB0, bV, oB[j], 0, 0, 0);
        }
        o9A = __builtin_amdgcn_mfma_f32_16x16x32_bf16(aPA0, vONE, o9A, 0, 0, 0);
        o9B = __builtin_amdgcn_mfma_f32_16x16x32_bf16(aPB0, vONE, o9B, 0, 0, 0);
        __builtin_amdgcn_s_setprio(0);

        if (pref) WRITELDS(cur ^ 1);                 // land next tile late
        __syncthreads();
        cur ^= 1;
    }
#undef LOADREGS
#undef WRITELDS

    if (split) {
        // Unnormalized partial write + per-row (l, m). c0 -> Oev, c1 -> Oab.
        ushort* dst = c ? Oab : Oev;
        float2* lm  = c ? lmO : lmE;
        #pragma unroll
        for (int r = 0; r < 4; ++r) {
            int row = qwave + quad * 4 + r;
            if (t16 == 0) {
                lm[(size_t)(row - 2048) * NH + hA] = make_float2(o9A[r], mA[r]);
                lm[(size_t)(row - 2048) * NH + hB] = make_float2(o9B[r], mB[r]);
            }
            #pragma unroll
            for (int j = 0; j < 8; ++j) {
                dst[(size_t)row * DIM + hA * HD + j * 16 + t16] = f2bf(oA[j][r]);
                dst[(size_t)row * DIM + hB * HD + j * 16 + t16] = f2bf(oB[j][r]);
            }
        }
    } else {
        #pragma unroll
        for (int r = 0; r < 4; ++r) {
            float invA = 1.f / fmaxf(o9A[r], 1e-20f);
            float invB = 1.f / fmaxf(o9B[r], 1e-20f);
            int row = qwave + quad * 4 + r;
            #pragma unroll
            for (int j = 0; j < 8; ++j) {
                Oab[(size_t)row * DIM + hA * HD + j * 16 + t16] = f2bf(oA[j][r] * invA);
                Oab[(size_t)row * DIM + hB * HD + j * 16 + t16] = f2bf(oB[j][r] * invB);
            }
        }
    }
}

// ---------------------------------------------------------------------------
// Exact flash split-k combine for rows 2048..4095:
// m* = max(mE,mO); o = (oE*e^{mE-m*} + oO*e^{mO-m*}) / (lE*e^{mE-m*}+lO*e^{mO-m*}).
// Reads oE (Xb), oO (Ab in place), writes final bf16 to Ab.
// ---------------------------------------------------------------------------
__global__ __launch_bounds__(256) void combine_kernel(
    const ushort* __restrict__ oE, const ushort* __restrict__ oO,
    const float2* __restrict__ lmE, const float2* __restrict__ lmO,
    ushort* __restrict__ out)
{
    size_t e = (size_t)(SEQ / 2) * DIM + ((size_t)blockIdx.x * 256 + threadIdx.x) * 8;
    int row = (int)(e >> 11);                  // DIM = 2048 = 2^11
    int h   = (int)((e >> 7) & 15);            // HD = 128 = 2^7
    float2 LE = lmE[(size_t)(row - 2048) * NH + h];
    float2 LO = lmO[(size_t)(row - 2048) * NH + h];
    float ms = fmaxf(LE.y, LO.y);
    float aE = __expf(LE.y - ms);
    float aO = __expf(LO.y - ms);
    float inv = 1.f / fmaxf(LE.x * aE + LO.x * aO, 1e-20f);
    aE *= inv; aO *= inv;
    VecU uE, uO, uR;
    uE.v = *(const uint4*)&oE[e];
    uO.v = *(const uint4*)&oO[e];
    #pragma unroll
    for (int j = 0; j < 8; ++j)
        uR.u[j] = f2bf(bf2f(uE.u[j]) * aE + bf2f(uO.u[j]) * aO);
    *(uint4*)&out[e] = uR.v;
}

// ---------------------------------------------------------------------------
// Memory plan:
//  d_ws (41.94 MB, proven):  Qb[4096][2048] | KVb[4096][1024] | Ab[4096][2048]
//    - pre-attn, Ab hosts WqT[2048][2048] + KVT[1024][2048] = contiguous
//      BT[3072][2048] for the fused QKV GEMM
//    - attn: Ab takes final rows <2048 + odd-chunk partials rows >=2048
//    - post-combine, KVb hosts WoT[2048][2048] (8.39 MB, exact fit)
//  d_out (33.55 MB fp32):    Xb bf16 [4096][2048] at 0 (16.78 MB; QKV input,
//                            then even-chunk partials rows >=2048), VT bf16
//                            [512][4096] at +16.78 MB, lmE/lmO (2x256 KB) at
//                            +20.97 MB. All consumed before the final GEMM.
// Launch list (8): cvt, convW, gemm_qkv, fuse3, attn, combine, convT(wo),
//                  gemm_tn.
// ---------------------------------------------------------------------------
extern "C" void kernel_launch(void* const* d_in, const int* in_sizes, int n_in,
                              void* d_out, int out_size, void* d_ws, size_t ws_size,
                              hipStream_t stream)
{
    const float* x  = (const float*)d_in[0];
    const float* fc = (const float*)d_in[2];
    const float* fs = (const float*)d_in[3];
    const float* wq = (const float*)d_in[5];
    const float* wk = (const float*)d_in[6];
    const float* wv = (const float*)d_in[7];
    const float* wo = (const float*)d_in[8];

    ushort* Qb  = (ushort*)d_ws;
    ushort* KVb = Qb + (size_t)SEQ * DIM;
    ushort* Ab  = KVb + (size_t)SEQ * KVLD;
    ushort* WqT = Ab;                                  // overlay (pre-attn)
    ushort* KVT = Ab + (size_t)DIM * DIM;              // overlay (pre-attn)
    ushort* WoT = KVb;                                 // overlay (post-attn)

    ushort* Xb = (ushort*)d_out;                       // bf16 x in d_out scratch
    ushort* VT = Xb + (size_t)SEQ * DIM;               // bf16 V^T [512][4096]
    float2* lmE = (float2*)(VT + (size_t)512 * SEQ);   // split-row (l,m) partials
    float2* lmO = lmE + (size_t)(SEQ / 2) * NH;

    dim3 blk(256);

    // Convert inputs to bf16 (x flat; wq|wk|wv transposed, one launch).
    cvt_kernel<<<(SEQ * DIM) / 2048, blk, 0, stream>>>(x, Xb);
    convW_kernel<<<dim3(96, 64), blk, 0, stream>>>(wq, wk, wv, WqT, KVT);

    // Fused QKV projection (BT = WqT|KVT contiguous at Ab, N=3072).
    gemm_qkv<<<dim3(3072 / 128, SEQ / 128), blk, 0, stream>>>(Xb, Ab, Qb, KVb);

    // RoPE(Q) + RoPE(K) + V-transpose, one launch (mutually independent).
    fuse3_kernel<<<16384 + 4096 + 2048, blk, 0, stream>>>(Qb, KVb, VT, fc, fs);

    // Flash attention: grid (8, 96) — 64 split-chunk blocks (qt>=32) +
    // 32 unsplit blocks (qt<32), heavy-first order, 3 blocks/CU.
    attn_kernel<<<dim3(NH / 2, 96), blk, 0, stream>>>(
        Qb, KVb, VT, Ab, Xb, lmE, lmO);

    // Merge split-row partials (rows 2048..4095) exactly.
    combine_kernel<<<(SEQ / 2) * DIM / 2048, blk, 0, stream>>>(
        Xb, Ab, lmE, lmO, Ab);

    // Output projection (WoT overlays KVb; writes fp32 d_out, consuming Xb/VT).
    convT_kernel<<<dim3(DIM / 32, DIM / 32), blk, 0, stream>>>(wo, WoT, DIM, DIM);
    gemm_tn<1><<<dim3(DIM / 128, SEQ / 128), blk, 0, stream>>>(Ab, WoT, d_out, SEQ, DIM, DIM);
}

// Round 10
// 430.063 us; speedup vs baseline: 1.1974x; 1.1974x over previous
//
#include <hip/hip_runtime.h>
#include <hip/hip_bf16.h>
#include <stdint.h>

#define SEQ 4096
#define DIM 2048
#define NH 16
#define NKV 4
#define HD 128
#define KVLD 1024   /* K|V fused row stride in KVb */

// External I/O is FP32 (proven round 2/6); internal tensors bf16.

using frag8 = __attribute__((ext_vector_type(8))) short;
using f32x4 = __attribute__((ext_vector_type(4))) float;

union VecU { ushort u[8]; uint4 v; };

__device__ __forceinline__ float bf2f(ushort u) {
    union { uint32_t u; float f; } v; v.u = ((uint32_t)u) << 16; return v.f;
}
__device__ __forceinline__ ushort f2bf(float f) {
    union { float f; uint32_t u; } v; v.f = f;
    uint32_t r = v.u + 0x7fffu + ((v.u >> 16) & 1u);
    return (ushort)(r >> 16);
}

__device__ __forceinline__ void glds16(const void* g, void* l) {
    __builtin_amdgcn_global_load_lds(
        (const __attribute__((address_space(1))) void*)g,
        (__attribute__((address_space(3))) void*)l, 16, 0, 0);
}

// ---------------------------------------------------------------------------
// Fused input prep, one launch (both parts depend only on kernel inputs):
//   b < 4096 : fp32 -> bf16 flat convert of x (8 elems/thread) -> Xb
//   b >= 4096: weight transpose wq|wk|wv fp32 [K][N] -> bf16 [N][K];
//              v = b-4096: bx = v%96, by = v/96 (the old convW grid).
// ---------------------------------------------------------------------------
__global__ __launch_bounds__(256) void prep_kernel(
    const float* __restrict__ x, const float* __restrict__ wq,
    const float* __restrict__ wk, const float* __restrict__ wv,
    ushort* __restrict__ Xb, ushort* __restrict__ WqT, ushort* __restrict__ KVT)
{
    __shared__ ushort T[32][36];
    int b = blockIdx.x;
    if (b < 4096) {
        size_t i = ((size_t)b * 256 + threadIdx.x) * 8;
        float4 f0 = *(const float4*)&x[i];
        float4 f1 = *(const float4*)&x[i + 4];
        VecU t;
        t.u[0] = f2bf(f0.x); t.u[1] = f2bf(f0.y); t.u[2] = f2bf(f0.z); t.u[3] = f2bf(f0.w);
        t.u[4] = f2bf(f1.x); t.u[5] = f2bf(f1.y); t.u[6] = f2bf(f1.z); t.u[7] = f2bf(f1.w);
        *(uint4*)&Xb[i] = t.v;
    } else {
        const int K = DIM;
        int v  = b - 4096;
        int bx = v % 96;
        int by = v / 96;
        const float* src; ushort* dst; int N, bn;
        if (bx < 64)      { src = wq; dst = WqT;                     N = DIM; bn = bx * 32; }
        else if (bx < 80) { src = wk; dst = KVT;                     N = 512; bn = (bx - 64) * 32; }
        else              { src = wv; dst = KVT + (size_t)512 * DIM; N = 512; bn = (bx - 80) * 32; }
        int r  = threadIdx.x >> 3;
        int c4 = (threadIdx.x & 7) * 4;
        int bk = by * 32;
        float4 w = *(const float4*)&src[(size_t)(bk + r) * N + bn + c4];
        T[r][c4]     = f2bf(w.x); T[r][c4 + 1] = f2bf(w.y);
        T[r][c4 + 2] = f2bf(w.z); T[r][c4 + 3] = f2bf(w.w);
        __syncthreads();
        ushort4 o;
        o.x = T[c4][r]; o.y = T[c4 + 1][r]; o.z = T[c4 + 2][r]; o.w = T[c4 + 3][r];
        *(ushort4*)&dst[(size_t)(bn + r) * K + bk + c4] = o;
    }
}

// ---------------------------------------------------------------------------
// Merged post-projection prep, one launch (all three parts independent):
//   b <  16384          : RoPE on Qb (16 heads, stride DIM, 1/sqrt(HD) folded)
//   16384 <= b < 20480  : RoPE on KVb K-half (4 heads, stride KVLD, cols<512)
//   b >= 20480          : V transpose KVb[t][512+d] -> VT[d][t] (reads cols>=512)
// ---------------------------------------------------------------------------
__global__ __launch_bounds__(256) void fuse3_kernel(
    ushort* __restrict__ Qb, ushort* __restrict__ KVb, ushort* __restrict__ VT,
    const float* __restrict__ Cos, const float* __restrict__ Sin)
{
    __shared__ ushort T[32][36];
    int b = blockIdx.x;
    if (b < 20480) {
        ushort* X; int log2nh, strideT, idx; float osc;
        if (b < 16384) { X = Qb;  log2nh = 4; strideT = DIM;  osc = 0.08838834764831845f; idx = b * 256 + threadIdx.x; }
        else           { X = KVb; log2nh = 2; strideT = KVLD; osc = 1.0f; idx = (b - 16384) * 256 + threadIdx.x; }
        int p = idx & 63;
        int h = (idx >> 6) & ((1 << log2nh) - 1);
        int t = idx >> (6 + log2nh);
        size_t base = (size_t)t * strideT + (size_t)h * 128 + 2 * p;
        ushort2 xv = *(ushort2*)&X[base];
        float x1 = bf2f(xv.x), x2 = bf2f(xv.y);
        float c = Cos[t * 64 + p], s = Sin[t * 64 + p];
        ushort2 ov;
        ov.x = f2bf((x1 * c - x2 * s) * osc);
        ov.y = f2bf((x1 * s + x2 * c) * osc);
        *(ushort2*)&X[base] = ov;
    } else {
        int v  = b - 20480;
        int bd = (v & 15) * 32;            // d-block
        int bt = (v >> 4) * 32;            // t-block
        int r  = threadIdx.x >> 3;
        int c4 = (threadIdx.x & 7) * 4;
        ushort4 w = *(const ushort4*)&KVb[(size_t)(bt + r) * KVLD + 512 + bd + c4];
        T[r][c4] = w.x; T[r][c4 + 1] = w.y; T[r][c4 + 2] = w.z; T[r][c4 + 3] = w.w;
        __syncthreads();
        ushort4 o;
        o.x = T[c4][r]; o.y = T[c4 + 1][r]; o.z = T[c4 + 2][r]; o.w = T[c4 + 3][r];
        *(ushort4*)&VT[(size_t)(bd + r) * SEQ + bt + c4] = o;
    }
}

// ---------------------------------------------------------------------------
// m97-style GEMM: C[M][N] = A[M][K] @ BT[N][K]^T, bf16 in; CF: fp32/bf16 out.
// 128x128 tile, BK=32, global_load_lds(16B).
// ---------------------------------------------------------------------------
template <int CF>
__global__ __launch_bounds__(256) void gemm_tn(
    const ushort* __restrict__ A, const ushort* __restrict__ BT,
    void* __restrict__ C, int M, int N, int K)
{
    __shared__ ushort As[128 * 32];
    __shared__ ushort Bs[128 * 32];

    const int tid  = threadIdx.x;
    const int lane = tid & 63;
    const int wave = tid >> 6;
    const int bm   = blockIdx.y * 128;
    const int bn   = blockIdx.x * 128;
    const int wm   = (wave >> 1) * 64;
    const int wn   = (wave & 1) * 64;
    const int quad = lane >> 4;
    const int t16  = lane & 15;
    const int kg   = quad ^ ((t16 >> 1) & 3);

    f32x4 acc[4][4] = {};

    for (int k0 = 0; k0 < K; k0 += 32) {
        #pragma unroll
        for (int it = 0; it < 2; ++it) {
            int gid = it * 256 + tid;
            int r   = gid >> 2;
            int cs  = (gid & 3) ^ ((gid >> 3) & 3);
            glds16(&A[(size_t)(bm + r) * K + k0 + cs * 8],
                   &As[(it * 256 + wave * 64) * 8]);
            glds16(&BT[(size_t)(bn + r) * K + k0 + cs * 8],
                   &Bs[(it * 256 + wave * 64) * 8]);
        }
        __syncthreads();

        frag8 af[4], bf[4];
        #pragma unroll
        for (int i = 0; i < 4; ++i)
            af[i] = *(const frag8*)&As[(wm + i * 16 + t16) * 32 + kg * 8];
        #pragma unroll
        for (int j = 0; j < 4; ++j)
            bf[j] = *(const frag8*)&Bs[(wn + j * 16 + t16) * 32 + kg * 8];
        #pragma unroll
        for (int i = 0; i < 4; ++i)
            #pragma unroll
            for (int j = 0; j < 4; ++j)
                acc[i][j] = __builtin_amdgcn_mfma_f32_16x16x32_bf16(
                    af[i], bf[j], acc[i][j], 0, 0, 0);
        __syncthreads();
    }

    #pragma unroll
    for (int i = 0; i < 4; ++i)
        #pragma unroll
        for (int j = 0; j < 4; ++j)
            #pragma unroll
            for (int r = 0; r < 4; ++r) {
                int row = bm + wm + i * 16 + quad * 4 + r;
                int col = bn + wn + j * 16 + t16;
                if (CF) ((float*)C)[(size_t)row * N + col] = acc[i][j][r];
                else    ((ushort*)C)[(size_t)row * N + col] = f2bf(acc[i][j][r]);
            }
}

// ---------------------------------------------------------------------------
// Fused QKV projection GEMM: A[SEQ][DIM] @ BT[3072][DIM]^T.
// BT rows 0..2047 = WqT, rows 2048..3071 = KVT (wk|wv) — contiguous at Ab.
// Block-uniform C split (2048 is 128-aligned): cols < 2048 -> Qb (ld DIM),
// cols >= 2048 -> KVb (ld KVLD). Grid 24x32 = 768 blocks.
// ---------------------------------------------------------------------------
__global__ __launch_bounds__(256) void gemm_qkv(
    const ushort* __restrict__ A, const ushort* __restrict__ BT,
    ushort* __restrict__ Cq, ushort* __restrict__ Ckv)
{
    const int K = DIM;
    __shared__ ushort As[128 * 32];
    __shared__ ushort Bs[128 * 32];

    const int tid  = threadIdx.x;
    const int lane = tid & 63;
    const int wave = tid >> 6;
    const int bm   = blockIdx.y * 128;
    const int bn   = blockIdx.x * 128;
    const int wm   = (wave >> 1) * 64;
    const int wn   = (wave & 1) * 64;
    const int quad = lane >> 4;
    const int t16  = lane & 15;
    const int kg   = quad ^ ((t16 >> 1) & 3);

    f32x4 acc[4][4] = {};

    for (int k0 = 0; k0 < K; k0 += 32) {
        #pragma unroll
        for (int it = 0; it < 2; ++it) {
            int gid = it * 256 + tid;
            int r   = gid >> 2;
            int cs  = (gid & 3) ^ ((gid >> 3) & 3);
            glds16(&A[(size_t)(bm + r) * K + k0 + cs * 8],
                   &As[(it * 256 + wave * 64) * 8]);
            glds16(&BT[(size_t)(bn + r) * K + k0 + cs * 8],
                   &Bs[(it * 256 + wave * 64) * 8]);
        }
        __syncthreads();

        frag8 af[4], bf[4];
        #pragma unroll
        for (int i = 0; i < 4; ++i)
            af[i] = *(const frag8*)&As[(wm + i * 16 + t16) * 32 + kg * 8];
        #pragma unroll
        for (int j = 0; j < 4; ++j)
            bf[j] = *(const frag8*)&Bs[(wn + j * 16 + t16) * 32 + kg * 8];
        #pragma unroll
        for (int i = 0; i < 4; ++i)
            #pragma unroll
            for (int j = 0; j < 4; ++j)
                acc[i][j] = __builtin_amdgcn_mfma_f32_16x16x32_bf16(
                    af[i], bf[j], acc[i][j], 0, 0, 0);
        __syncthreads();
    }

    // Block-uniform output select.
    ushort* C;
    int ldc, cb;
    if (bn < 2048) { C = Cq;  ldc = DIM;  cb = 0; }
    else           { C = Ckv; ldc = KVLD; cb = 2048; }

    #pragma unroll
    for (int i = 0; i < 4; ++i)
        #pragma unroll
        for (int j = 0; j < 4; ++j)
            #pragma unroll
            for (int r = 0; r < 4; ++r) {
                int row = bm + wm + i * 16 + quad * 4 + r;
                int col = bn + wn + j * 16 + t16;
                C[(size_t)row * ldc + (col - cb)] = f2bf(acc[i][j][r]);
            }
}

// ---------------------------------------------------------------------------
// Flash attention, causal, GQA, bf16 internal; head-paired blocks + KV-split.
// [Round-8 version VERBATIM — measured 148 us, VGPR 100, WRITE 25.6 MB, no
//  spill. Round-9's KVBLK=32 reg-prefetch spilled (WRITE 57 MB, VGPR 88 —
//  allocator spilled rather than extend staging live-ranges across the
//  compute phase) -> 241 us. Third spill from in-kernel reg staging (r2,
//  r6, r9): that approach is CLOSED for this kernel. Inter-block overlap
//  (3 blocks/CU via KV-split) is the working latency-hiding mechanism.]
// Grid (8, 96), heavy-first dispatch:
//   by <  64: qt = 63-(by>>1) in [32,63]; chunk c = by&1 of KV range in
//             contiguous halves (c0 mask-free). UNNORMALIZED partial o +
//             per-row (l, m) — exact flash split-k. c0 -> Oev, c1 -> Oab.
//   by >= 64: qt = 95-by in [0,31], unsplit, normalized direct write.
// combine merges rows 2048+ exactly. Spec-softmax (m=0 init, lane-local
// trigger, full fixup if __any(lm > m+8) — never for this data, exact for
// any). Row-sum via ones-MFMA. Scores pre-scaled (1/sqrt(HD) in Q).
// T5 setprio on MFMA clusters.
// ---------------------------------------------------------------------------
__global__ __launch_bounds__(256, 2) void attn_kernel(
    const ushort* __restrict__ Q, const ushort* __restrict__ Kb,
    const ushort* __restrict__ VT, ushort* __restrict__ Oab,
    ushort* __restrict__ Oev, float2* __restrict__ lmE, float2* __restrict__ lmO)
{
    __shared__ ushort Ks[64][136];      // [t][d], padded
    __shared__ ushort Vt[128][72];      // [d][t], padded
    __shared__ ushort Sp[4][32][72];    // per-wave P tiles: rows 0-15 head A, 16-31 head B

    const int tid  = threadIdx.x;
    const int lane = tid & 63;
    const int wave = tid >> 6;
    const int quad = lane >> 4;
    const int t16  = lane & 15;
    const int hp   = blockIdx.x;        // head pair 0..7
    const int hA   = 2 * hp;
    const int hB   = 2 * hp + 1;
    const int kvh  = hp >> 1;

    frag8 vONE;
    #pragma unroll
    for (int i = 0; i < 8; ++i) vONE[i] = (short)0x3F80;   // bf16 1.0

    const int by = (int)blockIdx.y;
    int qt, c, split;
    if (by < 64) { split = 1; qt = 63 - (by >> 1); c = by & 1; }
    else         { split = 0; qt = 95 - by;        c = 0;      }
    const int n  = qt + 1;                       // total 64-KV tiles
    const int q0 = qt * 64;
    const int qwave = q0 + wave * 16;
    const int qmaxw = qwave + 15;
    const int tstart = (split && c) ? (n / 2) * 64 : 0;
    const int tend   = (split && !c) ? (n / 2) * 64 : n * 64;

    frag8 aQA[4], aQB[4];
    #pragma unroll
    for (int kk = 0; kk < 4; ++kk) {
        aQA[kk] = *(const frag8*)&Q[(size_t)(qwave + t16) * DIM + hA * HD + kk * 32 + quad * 8];
        aQB[kk] = *(const frag8*)&Q[(size_t)(qwave + t16) * DIM + hB * HD + kk * 32 + quad * 8];
    }

    f32x4 oA[8] = {}, oB[8] = {};
    f32x4 o9A = {0.f, 0.f, 0.f, 0.f};
    f32x4 o9B = {0.f, 0.f, 0.f, 0.f};
    float mA[4] = {0.f, 0.f, 0.f, 0.f};
    float mB[4] = {0.f, 0.f, 0.f, 0.f};

    for (int t0 = tstart; t0 < tend; t0 += 64) {
        // Stage K tile: 64 rows x 128 d (uint4 from fused KVb).
        #pragma unroll
        for (int it = 0; it < 4; ++it) {
            int idx = tid + it * 256;
            int tt  = idx >> 4;
            int cc  = (idx & 15) * 8;
            *(uint4*)&Ks[tt][cc] =
                *(const uint4*)&Kb[(size_t)(t0 + tt) * KVLD + kvh * HD + cc];
        }
        // Stage V^T tile: 128 d x 64 t (uint4 from pre-transposed VT).
        #pragma unroll
        for (int it = 0; it < 4; ++it) {
            int idx = tid + it * 256;
            int d   = idx >> 3;                // 0..127
            int tq  = (idx & 7) * 8;           // 0..56
            *(uint4*)&Vt[d][tq] =
                *(const uint4*)&VT[(size_t)(kvh * HD + d) * SEQ + t0 + tq];
        }
        __syncthreads();

        const bool hi = (t0 + 32 <= qmaxw);    // wave-uniform upper-half guard

        f32x4 sA0 = {0.f,0.f,0.f,0.f}, sA1 = {0.f,0.f,0.f,0.f};
        f32x4 sA2 = {0.f,0.f,0.f,0.f}, sA3 = {0.f,0.f,0.f,0.f};
        f32x4 sB0 = {0.f,0.f,0.f,0.f}, sB1 = {0.f,0.f,0.f,0.f};
        f32x4 sB2 = {0.f,0.f,0.f,0.f}, sB3 = {0.f,0.f,0.f,0.f};

        __builtin_amdgcn_s_setprio(1);
        #pragma unroll
        for (int kk = 0; kk < 4; ++kk) {
            frag8 b0 = *(const frag8*)&Ks[2 * t16][kk * 32 + quad * 8];
            frag8 b1 = *(const frag8*)&Ks[2 * t16 + 1][kk * 32 + quad * 8];
            sA0 = __builtin_amdgcn_mfma_f32_16x16x32_bf16(aQA[kk], b0, sA0, 0, 0, 0);
            sB0 = __builtin_amdgcn_mfma_f32_16x16x32_bf16(aQB[kk], b0, sB0, 0, 0, 0);
            sA1 = __builtin_amdgcn_mfma_f32_16x16x32_bf16(aQA[kk], b1, sA1, 0, 0, 0);
            sB1 = __builtin_amdgcn_mfma_f32_16x16x32_bf16(aQB[kk], b1, sB1, 0, 0, 0);
        }
        if (hi) {
            #pragma unroll
            for (int kk = 0; kk < 4; ++kk) {
                frag8 b2 = *(const frag8*)&Ks[32 + 2 * t16][kk * 32 + quad * 8];
                frag8 b3 = *(const frag8*)&Ks[33 + 2 * t16][kk * 32 + quad * 8];
                sA2 = __builtin_amdgcn_mfma_f32_16x16x32_bf16(aQA[kk], b2, sA2, 0, 0, 0);
                sB2 = __builtin_amdgcn_mfma_f32_16x16x32_bf16(aQB[kk], b2, sB2, 0, 0, 0);
                sA3 = __builtin_amdgcn_mfma_f32_16x16x32_bf16(aQA[kk], b3, sA3, 0, 0, 0);
                sB3 = __builtin_amdgcn_mfma_f32_16x16x32_bf16(aQB[kk], b3, sB3, 0, 0, 0);
            }
        }
        __builtin_amdgcn_s_setprio(0);

        const bool mLo = (t0 + 31 > qwave);        // wave-uniform
        const bool mHi = (t0 + 63 > qwave);

        // Fast path: speculative exp against running m; lane-local trigger.
        bool trig = false;
        #pragma unroll
        for (int r = 0; r < 4; ++r) {
            int q = qwave + quad * 4 + r;
            bool x0 = mLo && (t0 + 2 * t16 > q);
            bool x1 = mLo && (t0 + 2 * t16 + 1 > q);
            bool x2 = mHi && (t0 + 32 + 2 * t16 > q);
            bool x3 = mHi && (t0 + 33 + 2 * t16 > q);
            float vA0 = x0 ? -30000.f : sA0[r];
            float vA1 = x1 ? -30000.f : sA1[r];
            float vA2 = (hi && !x2) ? sA2[r] : -30000.f;
            float vA3 = (hi && !x3) ? sA3[r] : -30000.f;
            float vB0 = x0 ? -30000.f : sB0[r];
            float vB1 = x1 ? -30000.f : sB1[r];
            float vB2 = (hi && !x2) ? sB2[r] : -30000.f;
            float vB3 = (hi && !x3) ? sB3[r] : -30000.f;
            float lmA = fmaxf(fmaxf(vA0, vA1), fmaxf(vA2, vA3));
            float lmB = fmaxf(fmaxf(vB0, vB1), fmaxf(vB2, vB3));
            trig |= (lmA > mA[r] + 8.f) | (lmB > mB[r] + 8.f);
            float eA0 = __expf(vA0 - mA[r]);
            float eA1 = __expf(vA1 - mA[r]);
            float eB0 = __expf(vB0 - mB[r]);
            float eB1 = __expf(vB1 - mB[r]);
            *(uint*)&Sp[wave][quad * 4 + r][2 * t16] =
                (uint)f2bf(eA0) | ((uint)f2bf(eA1) << 16);
            *(uint*)&Sp[wave][16 + quad * 4 + r][2 * t16] =
                (uint)f2bf(eB0) | ((uint)f2bf(eB1) << 16);
            if (hi) {
                float eA2 = __expf(vA2 - mA[r]);
                float eA3 = __expf(vA3 - mA[r]);
                float eB2 = __expf(vB2 - mB[r]);
                float eB3 = __expf(vB3 - mB[r]);
                *(uint*)&Sp[wave][quad * 4 + r][32 + 2 * t16] =
                    (uint)f2bf(eA2) | ((uint)f2bf(eA3) << 16);
                *(uint*)&Sp[wave][16 + quad * 4 + r][32 + 2 * t16] =
                    (uint)f2bf(eB2) | ((uint)f2bf(eB3) << 16);
            }
        }

        // Rare fixup: full cross-lane max, rescale, recompute + rewrite P.
        if (__any(trig)) {
            #pragma unroll
            for (int r = 0; r < 4; ++r) {
                int q = qwave + quad * 4 + r;
                bool x0 = mLo && (t0 + 2 * t16 > q);
                bool x1 = mLo && (t0 + 2 * t16 + 1 > q);
                bool x2 = mHi && (t0 + 32 + 2 * t16 > q);
                bool x3 = mHi && (t0 + 33 + 2 * t16 > q);
                float vA0 = x0 ? -30000.f : sA0[r];
                float vA1 = x1 ? -30000.f : sA1[r];
                float vA2 = (hi && !x2) ? sA2[r] : -30000.f;
                float vA3 = (hi && !x3) ? sA3[r] : -30000.f;
                float vB0 = x0 ? -30000.f : sB0[r];
                float vB1 = x1 ? -30000.f : sB1[r];
                float vB2 = (hi && !x2) ? sB2[r] : -30000.f;
                float vB3 = (hi && !x3) ? sB3[r] : -30000.f;
                float rmA = fmaxf(fmaxf(vA0, vA1), fmaxf(vA2, vA3));
                float rmB = fmaxf(fmaxf(vB0, vB1), fmaxf(vB2, vB3));
                rmA = fmaxf(rmA, __shfl_xor(rmA, 1));
                rmA = fmaxf(rmA, __shfl_xor(rmA, 2));
                rmA = fmaxf(rmA, __shfl_xor(rmA, 4));
                rmA = fmaxf(rmA, __shfl_xor(rmA, 8));
                rmB = fmaxf(rmB, __shfl_xor(rmB, 1));
                rmB = fmaxf(rmB, __shfl_xor(rmB, 2));
                rmB = fmaxf(rmB, __shfl_xor(rmB, 4));
                rmB = fmaxf(rmB, __shfl_xor(rmB, 8));
                float mnA = fmaxf(mA[r], rmA);
                float mnB = fmaxf(mB[r], rmB);
                float alA = __expf(mA[r] - mnA);
                float alB = __expf(mB[r] - mnB);
                #pragma unroll
                for (int j = 0; j < 8; ++j) { oA[j][r] *= alA; oB[j][r] *= alB; }
                o9A[r] *= alA; o9B[r] *= alB;
                mA[r] = mnA; mB[r] = mnB;
                float eA0 = __expf(vA0 - mnA);
                float eA1 = __expf(vA1 - mnA);
                float eB0 = __expf(vB0 - mnB);
                float eB1 = __expf(vB1 - mnB);
                *(uint*)&Sp[wave][quad * 4 + r][2 * t16] =
                    (uint)f2bf(eA0) | ((uint)f2bf(eA1) << 16);
                *(uint*)&Sp[wave][16 + quad * 4 + r][2 * t16] =
                    (uint)f2bf(eB0) | ((uint)f2bf(eB1) << 16);
                if (hi) {
                    float eA2 = __expf(vA2 - mnA);
                    float eA3 = __expf(vA3 - mnA);
                    float eB2 = __expf(vB2 - mnB);
                    float eB3 = __expf(vB3 - mnB);
                    *(uint*)&Sp[wave][quad * 4 + r][32 + 2 * t16] =
                        (uint)f2bf(eA2) | ((uint)f2bf(eA3) << 16);
                    *(uint*)&Sp[wave][16 + quad * 4 + r][32 + 2 * t16] =
                        (uint)f2bf(eB2) | ((uint)f2bf(eB3) << 16);
                }
            }
        }

        frag8 aPA0 = *(const frag8*)&Sp[wave][t16][quad * 8];
        frag8 aPB0 = *(const frag8*)&Sp[wave][16 + t16][quad * 8];
        __builtin_amdgcn_s_setprio(1);
        #pragma unroll
        for (int j = 0; j < 8; ++j) {
            frag8 bV = *(const frag8*)&Vt[j * 16 + t16][quad * 8];
            oA[j] = __builtin_amdgcn_mfma_f32_16x16x32_bf16(aPA0, bV, oA[j], 0, 0, 0);
            oB[j] = __builtin_amdgcn_mfma_f32_16x16x32_bf16(aPB0, bV, oB[j], 0, 0, 0);
        }
        o9A = __builtin_amdgcn_mfma_f32_16x16x32_bf16(aPA0, vONE, o9A, 0, 0, 0);
        o9B = __builtin_amdgcn_mfma_f32_16x16x32_bf16(aPB0, vONE, o9B, 0, 0, 0);
        if (hi) {
            frag8 aPA1 = *(const frag8*)&Sp[wave][t16][32 + quad * 8];
            frag8 aPB1 = *(const frag8*)&Sp[wave][16 + t16][32 + quad * 8];
            #pragma unroll
            for (int j = 0; j < 8; ++j) {
                frag8 bV = *(const frag8*)&Vt[j * 16 + t16][32 + quad * 8];
                oA[j] = __builtin_amdgcn_mfma_f32_16x16x32_bf16(aPA1, bV, oA[j], 0, 0, 0);
                oB[j] = __builtin_amdgcn_mfma_f32_16x16x32_bf16(aPB1, bV, oB[j], 0, 0, 0);
            }
            o9A = __builtin_amdgcn_mfma_f32_16x16x32_bf16(aPA1, vONE, o9A, 0, 0, 0);
            o9B = __builtin_amdgcn_mfma_f32_16x16x32_bf16(aPB1, vONE, o9B, 0, 0, 0);
        }
        __builtin_amdgcn_s_setprio(0);
        __syncthreads();
    }

    if (split) {
        // Unnormalized partial write + per-row (l, m). c0 -> Oev, c1 -> Oab.
        ushort* dst = c ? Oab : Oev;
        float2* lm  = c ? lmO : lmE;
        #pragma unroll
        for (int r = 0; r < 4; ++r) {
            int row = qwave + quad * 4 + r;
            if (t16 == 0) {
                lm[(size_t)(row - 2048) * NH + hA] = make_float2(o9A[r], mA[r]);
                lm[(size_t)(row - 2048) * NH + hB] = make_float2(o9B[r], mB[r]);
            }
            #pragma unroll
            for (int j = 0; j < 8; ++j) {
                dst[(size_t)row * DIM + hA * HD + j * 16 + t16] = f2bf(oA[j][r]);
                dst[(size_t)row * DIM + hB * HD + j * 16 + t16] = f2bf(oB[j][r]);
            }
        }
    } else {
        #pragma unroll
        for (int r = 0; r < 4; ++r) {
            float invA = 1.f / fmaxf(o9A[r], 1e-20f);
            float invB = 1.f / fmaxf(o9B[r], 1e-20f);
            int row = qwave + quad * 4 + r;
            #pragma unroll
            for (int j = 0; j < 8; ++j) {
                Oab[(size_t)row * DIM + hA * HD + j * 16 + t16] = f2bf(oA[j][r] * invA);
                Oab[(size_t)row * DIM + hB * HD + j * 16 + t16] = f2bf(oB[j][r] * invB);
            }
        }
    }
}

// ---------------------------------------------------------------------------
// Fused post-attention, one launch (both parts independent; both require
// attn done — combine reads attn partials, convT writes WoT over KVb):
//   b < 2048 : exact flash split-k combine for rows 2048..4095
//   b >= 2048: wo transpose fp32 [2048][2048] -> bf16 WoT [2048][2048];
//              v = b-2048: bn = (v&63)*32, bk = (v>>6)*32.
// ---------------------------------------------------------------------------
__global__ __launch_bounds__(256) void post_kernel(
    const ushort* __restrict__ oE, const ushort* __restrict__ oO,
    const float2* __restrict__ lmE, const float2* __restrict__ lmO,
    ushort* __restrict__ out, const float* __restrict__ wo,
    ushort* __restrict__ WoT)
{
    __shared__ ushort T[32][36];
    int b = blockIdx.x;
    if (b < 2048) {
        size_t e = (size_t)(SEQ / 2) * DIM + ((size_t)b * 256 + threadIdx.x) * 8;
        int row = (int)(e >> 11);                  // DIM = 2048 = 2^11
        int h   = (int)((e >> 7) & 15);            // HD = 128 = 2^7
        float2 LE = lmE[(size_t)(row - 2048) * NH + h];
        float2 LO = lmO[(size_t)(row - 2048) * NH + h];
        float ms = fmaxf(LE.y, LO.y);
        float aE = __expf(LE.y - ms);
        float aO = __expf(LO.y - ms);
        float inv = 1.f / fmaxf(LE.x * aE + LO.x * aO, 1e-20f);
        aE *= inv; aO *= inv;
        VecU uE, uO, uR;
        uE.v = *(const uint4*)&oE[e];
        uO.v = *(const uint4*)&oO[e];
        #pragma unroll
        for (int j = 0; j < 8; ++j)
            uR.u[j] = f2bf(bf2f(uE.u[j]) * aE + bf2f(uO.u[j]) * aO);
        *(uint4*)&out[e] = uR.v;
    } else {
        int v  = b - 2048;
        int bn = (v & 63) * 32;
        int bk = (v >> 6) * 32;
        int r  = threadIdx.x >> 3;
        int c4 = (threadIdx.x & 7) * 4;
        float4 w = *(const float4*)&wo[(size_t)(bk + r) * DIM + bn + c4];
        T[r][c4]     = f2bf(w.x); T[r][c4 + 1] = f2bf(w.y);
        T[r][c4 + 2] = f2bf(w.z); T[r][c4 + 3] = f2bf(w.w);
        __syncthreads();
        ushort4 o;
        o.x = T[c4][r]; o.y = T[c4 + 1][r]; o.z = T[c4 + 2][r]; o.w = T[c4 + 3][r];
        *(ushort4*)&WoT[(size_t)(bn + r) * DIM + bk + c4] = o;
    }
}

// ---------------------------------------------------------------------------
// Memory plan:
//  d_ws (41.94 MB, proven):  Qb[4096][2048] | KVb[4096][1024] | Ab[4096][2048]
//    - pre-attn, Ab hosts WqT[2048][2048] + KVT[1024][2048] = contiguous
//      BT[3072][2048] for the fused QKV GEMM
//    - attn: Ab takes final rows <2048 + odd-chunk partials rows >=2048
//    - post: KVb hosts WoT[2048][2048] (8.39 MB, exact fit)
//  d_out (33.55 MB fp32):    Xb bf16 [4096][2048] at 0 (16.78 MB; QKV input,
//                            then even-chunk partials rows >=2048), VT bf16
//                            [512][4096] at +16.78 MB, lmE/lmO (2x256 KB) at
//                            +20.97 MB. All consumed before the final GEMM.
// Launch list (6): prep(cvt|convW), gemm_qkv, fuse3, attn,
//                  post(combine|convT-wo), gemm_tn.
// ---------------------------------------------------------------------------
extern "C" void kernel_launch(void* const* d_in, const int* in_sizes, int n_in,
                              void* d_out, int out_size, void* d_ws, size_t ws_size,
                              hipStream_t stream)
{
    const float* x  = (const float*)d_in[0];
    const float* fc = (const float*)d_in[2];
    const float* fs = (const float*)d_in[3];
    const float* wq = (const float*)d_in[5];
    const float* wk = (const float*)d_in[6];
    const float* wv = (const float*)d_in[7];
    const float* wo = (const float*)d_in[8];

    ushort* Qb  = (ushort*)d_ws;
    ushort* KVb = Qb + (size_t)SEQ * DIM;
    ushort* Ab  = KVb + (size_t)SEQ * KVLD;
    ushort* WqT = Ab;                                  // overlay (pre-attn)
    ushort* KVT = Ab + (size_t)DIM * DIM;              // overlay (pre-attn)
    ushort* WoT = KVb;                                 // overlay (post-attn)

    ushort* Xb = (ushort*)d_out;                       // bf16 x in d_out scratch
    ushort* VT = Xb + (size_t)SEQ * DIM;               // bf16 V^T [512][4096]
    float2* lmE = (float2*)(VT + (size_t)512 * SEQ);   // split-row (l,m) partials
    float2* lmO = lmE + (size_t)(SEQ / 2) * NH;

    dim3 blk(256);

    // Input prep: x -> bf16 Xb, wq|wk|wv -> transposed bf16 (one launch).
    prep_kernel<<<4096 + 96 * 64, blk, 0, stream>>>(x, wq, wk, wv, Xb, WqT, KVT);

    // Fused QKV projection (BT = WqT|KVT contiguous at Ab, N=3072).
    gemm_qkv<<<dim3(3072 / 128, SEQ / 128), blk, 0, stream>>>(Xb, Ab, Qb, KVb);

    // RoPE(Q) + RoPE(K) + V-transpose, one launch (mutually independent).
    fuse3_kernel<<<16384 + 4096 + 2048, blk, 0, stream>>>(Qb, KVb, VT, fc, fs);

    // Flash attention: grid (8, 96) — 64 split-chunk blocks (qt>=32) +
    // 32 unsplit blocks (qt<32), heavy-first order, 3 blocks/CU.
    attn_kernel<<<dim3(NH / 2, 96), blk, 0, stream>>>(
        Qb, KVb, VT, Ab, Xb, lmE, lmO);

    // Combine split-row partials + wo transpose (one launch).
    post_kernel<<<2048 + 64 * 64, blk, 0, stream>>>(
        Xb, Ab, lmE, lmO, Ab, wo, WoT);

    // Output projection (writes fp32 d_out, consuming Xb/VT).
    gemm_tn<1><<<dim3(DIM / 128, SEQ / 128), blk, 0, stream>>>(Ab, WoT, d_out, SEQ, DIM, DIM);
}